// Round 6
// baseline (1352.823 us; speedup 1.0000x reference)
//
#include <hip/hip_runtime.h>
#include <stdint.h>

// ---------------------------------------------------------------------------
// MultiHeadAdaptiveChebyshevLayer, round 8: persistent 4-row blocks.
// Counter history (main kernel): A=R0 struct (1r/blk, y2 regs, cap128,
// 1blk/CU) = 105 us; every tight-cap variant spilled (R2: 64-cap huge spill
// 210; R4: 64-cap mild spill 139; R5: 64-cap reported VGPR=32, 480 MB
// scratch, 362).  Lesson: never cap below the natural ~100-reg live set.
// R5's counters also calibrated the fixed tax: ~218 us/iter (1 GiB ws
// poison 165.7 + out poison ~42 + prolog/launch ~8).
//
// A's remaining inefficiency: 1 blk/CU + per-block terminal store burst =
// the CU idles ~10 us per row while the retiring block's 256 KB of NT
// stores drain.  Fix WITHOUT changing the register regime: persistent
// blocks (grid=256, 1/CU) looping over 4 rows; row r+1's staging+compute
// overlaps row r's store drain inside the same waves.  Only the last row's
// drain is exposed.
//
// Ownership per row (unchanged from A): thread t owns features
// f = c*4096 + t*4 + {0..3}, c = 0..15; p = c*512 + (t>>1), k = (t&1)*4+d.
// W3[(c*4+d)*1024+t] = folded bf16x8 coeffs; GB3[c*1024+t] = packed g/b.
// ---------------------------------------------------------------------------

#define LN_EPS 1e-5f

typedef float vfloat4 __attribute__((ext_vector_type(4)));

__device__ __forceinline__ unsigned bf16_rne(float f) {
    unsigned u = __float_as_uint(f);
    unsigned r = u + 0x7fffu + ((u >> 16) & 1u);
    return r >> 16;
}
__device__ __forceinline__ float bf_lo(unsigned u) { return __uint_as_float(u << 16); }
__device__ __forceinline__ float bf_hi(unsigned u) { return __uint_as_float(u & 0xffff0000u); }

// Prologue 1: fold poly into kernel, bf16-pack over m, permute so the main
// kernel's load for (c,d) at lane t is W3[(c*4+d)*1024 + t].
__global__ void fold_weights_kernel(const float* __restrict__ K,
                                    const float* __restrict__ poly,
                                    uint4* __restrict__ W3) {
    int tid = blockIdx.x * blockDim.x + threadIdx.x;   // [0, 65536)
    int p = tid >> 3, k = tid & 7;
    const float* kp = K + (size_t)p * 64 + k;          // stride 8 over m
    float pw = poly[p * 8 + k];
    float v[8];
#pragma unroll
    for (int m = 0; m < 8; ++m) v[m] = kp[m * 8] * pw;
    uint4 q;
    q.x = bf16_rne(v[0]) | (bf16_rne(v[1]) << 16);
    q.y = bf16_rne(v[2]) | (bf16_rne(v[3]) << 16);
    q.z = bf16_rne(v[4]) | (bf16_rne(v[5]) << 16);
    q.w = bf16_rne(v[6]) | (bf16_rne(v[7]) << 16);
    int c = p >> 9;
    int t = ((p & 511) << 1) | (k >> 2);
    int d = k & 3;
    W3[(c * 4 + d) * 1024 + t] = q;
}

// Prologue 2: GB3[tid] covers features f = tid*4 .. +3; each word packs
// (bf16(gamma) | bf16(beta)<<16).
__global__ void pack_gb_kernel(const float* __restrict__ gamma,
                               const float* __restrict__ beta,
                               uint4* __restrict__ GB3) {
    int tid = blockIdx.x * blockDim.x + threadIdx.x;   // [0, 16384)
    float4 g = ((const float4*)gamma)[tid];
    float4 b = ((const float4*)beta)[tid];
    uint4 q;
    q.x = bf16_rne(g.x) | (bf16_rne(b.x) << 16);
    q.y = bf16_rne(g.y) | (bf16_rne(b.y) << 16);
    q.z = bf16_rne(g.z) | (bf16_rne(b.z) << 16);
    q.w = bf16_rne(g.w) | (bf16_rne(b.w) << 16);
    GB3[tid] = q;
}

// 8-term Chebyshev dot against one packed-bf16 quad (T1..T7 in scope).
#define CHEB_DOT(q, acc)                                                      \
    {                                                                         \
        float c0 = bf_lo(q.x), c1 = bf_hi(q.x);                               \
        float c2 = bf_lo(q.y), c3 = bf_hi(q.y);                               \
        float c4 = bf_lo(q.z), c5 = bf_hi(q.z);                               \
        float c6 = bf_lo(q.w), c7 = bf_hi(q.w);                               \
        acc = fmaf(T1, c1, c0);                                               \
        acc = fmaf(T2, c2, acc);                                              \
        acc = fmaf(T3, c3, acc);                                              \
        acc = fmaf(T4, c4, acc);                                              \
        acc = fmaf(T5, c5, acc);                                              \
        acc = fmaf(T6, c6, acc);                                              \
        acc = fmaf(T7, c7, acc);                                              \
    }

// Main: persistent blocks — grid 256 (1/CU), each block does rows
// b, b+256, b+512, b+768.  Register regime identical to the proven A
// kernel: (1024, 4) -> 128-VGPR cap, y2[32] fits, no spill.
__global__ __launch_bounds__(1024, 4) void cheb_ln_main(
    const float* __restrict__ x, const float* __restrict__ scale,
    const uint4* __restrict__ W3, const uint4* __restrict__ GB3,
    float* __restrict__ out) {
    __shared__ float xs[8192];
    __shared__ float red[32];
    const int t = threadIdx.x;
    const int w = t >> 6, l = t & 63;
    const int phalf = t >> 1;

    // Stage row 0: xs[h*1024+i] = x[i]*scale[h*1024+i].
    {
        const int r = blockIdx.x;
        float xv = x[(size_t)r * 1024 + t];
#pragma unroll
        for (int h = 0; h < 8; ++h)
            xs[h * 1024 + t] = xv * scale[h * 1024 + t];
    }
    __syncthreads();

    for (int j = 0; j < 4; ++j) {
        const int r = blockIdx.x + j * 256;

        unsigned y2[32];            // 64 y values as packed bf16 pairs
        float sum = 0.f, sq = 0.f;

#pragma unroll
        for (int c = 0; c < 16; ++c) {
            float v = xs[c * 512 + phalf];      // 2-way broadcast, free
            float v2 = v + v;
            float T1 = v;
            float T2 = fmaf(v2, T1, -1.f);
            float T3 = fmaf(v2, T2, -T1);
            float T4 = fmaf(v2, T3, -T2);
            float T5 = fmaf(v2, T4, -T3);
            float T6 = fmaf(v2, T5, -T4);
            float T7 = fmaf(v2, T6, -T5);

            float a0, a1, a2, a3;
            {
                uint4 q0 = W3[(c * 4 + 0) * 1024 + t];
                uint4 q1 = W3[(c * 4 + 1) * 1024 + t];
                CHEB_DOT(q0, a0);
                CHEB_DOT(q1, a1);
            }
            {
                uint4 q2 = W3[(c * 4 + 2) * 1024 + t];
                uint4 q3 = W3[(c * 4 + 3) * 1024 + t];
                CHEB_DOT(q2, a2);
                CHEB_DOT(q3, a3);
            }

            sum += (a0 + a1) + (a2 + a3);
            sq = fmaf(a0, a0, sq); sq = fmaf(a1, a1, sq);
            sq = fmaf(a2, a2, sq); sq = fmaf(a3, a3, sq);
            y2[c * 2 + 0] = bf16_rne(a0) | (bf16_rne(a1) << 16);
            y2[c * 2 + 1] = bf16_rne(a2) | (bf16_rne(a3) << 16);
        }

        // Wave reduce (64 lanes), then cross-wave via LDS.
#pragma unroll
        for (int off = 32; off; off >>= 1) {
            sum += __shfl_down(sum, off, 64);
            sq  += __shfl_down(sq,  off, 64);
        }
        if (l == 0) { red[w] = sum; red[w + 16] = sq; }
        __syncthreads();                        // also: all pass-1 xs reads done
        float S = 0.f, SQ = 0.f;
#pragma unroll
        for (int q = 0; q < 16; ++q) { S += red[q]; SQ += red[q + 16]; }
        const float inv = 1.f / 65536.f;
        float mu = S * inv;
        float var = fmaf(-mu, mu, SQ * inv);
        float rstd = rsqrtf(var + LN_EPS);

        // Stage row j+1 into xs NOW (xs is dead; barrier above covers the
        // overwrite).  The global loads issue before the store burst and
        // their latency hides under the epilogue VALU below.
        if (j < 3) {
            const int rn = blockIdx.x + (j + 1) * 256;
            float xv = x[(size_t)rn * 1024 + t];
#pragma unroll
            for (int h = 0; h < 8; ++h)
                xs[h * 1024 + t] = xv * scale[h * 1024 + t];
        }

        // Epilogue: unpack y, normalize, affine, NT coalesced stores.  The
        // stores drain in the background of the next row's compute.
        float* orow = out + (size_t)r * 65536;
#pragma unroll
        for (int c = 0; c < 16; ++c) {
            uint4 g = GB3[c * 1024 + t];
            unsigned u0 = y2[c * 2 + 0], u1 = y2[c * 2 + 1];
            vfloat4 o;
            o.x = fmaf((bf_lo(u0) - mu) * rstd, bf_lo(g.x), bf_hi(g.x));
            o.y = fmaf((bf_hi(u0) - mu) * rstd, bf_lo(g.y), bf_hi(g.y));
            o.z = fmaf((bf_lo(u1) - mu) * rstd, bf_lo(g.z), bf_hi(g.z));
            o.w = fmaf((bf_hi(u1) - mu) * rstd, bf_lo(g.w), bf_hi(g.w));
            __builtin_nontemporal_store(o, (vfloat4*)(orow + c * 4096 + t * 4));
        }
        __syncthreads();                        // stage writes visible to all
    }
}

extern "C" void kernel_launch(void* const* d_in, const int* in_sizes, int n_in,
                              void* d_out, int out_size, void* d_ws, size_t ws_size,
                              hipStream_t stream) {
    const float* x     = (const float*)d_in[0];   // [1024,1024]
    const float* scale = (const float*)d_in[1];   // [8,1024]
    const float* poly  = (const float*)d_in[2];   // [8,1024,8]
    const float* kern  = (const float*)d_in[3];   // [8,1024,8,8]
    const float* gamma = (const float*)d_in[4];   // [65536]
    const float* beta  = (const float*)d_in[5];   // [65536]
    float* out = (float*)d_out;

    uint4* W3  = (uint4*)d_ws;                          // 1 MiB
    uint4* GB3 = (uint4*)((char*)d_ws + (1u << 20));    // 256 KiB

    fold_weights_kernel<<<256, 256, 0, stream>>>(kern, poly, W3);
    pack_gb_kernel<<<64, 256, 0, stream>>>(gamma, beta, GB3);
    cheb_ln_main<<<256, 1024, 0, stream>>>(x, scale, W3, GB3, out);
}

// Round 7
// 347.809 us; speedup vs baseline: 3.8896x; 3.8896x over previous
//
#include <hip/hip_runtime.h>
#include <stdint.h>

// ---------------------------------------------------------------------------
// MultiHeadAdaptiveChebyshevLayer, round 9: R5's two-pass body at (1024,4).
//
// Compiler model (R2/R3/R5/R6 counters): hipcc targets ONE occupancy step
// beyond the __launch_bounds__ minimum and spills to get there:
//   (1024,1) -> ~130 VGPR used;  (1024,4) -> 64;  (1024,8) -> 32.
// So the winning configuration is a live set that FITS 64 registers at
// (1024,4): the compiler then gives 64 VGPR + zero spill + 2 blocks/CU
// (LDS 66 KB x 2 = 132 < 160 KB).  The two-pass recompute body (no y2[]
// register array; y recomputed in pass 2 from L2-hot W3) has live ~35-40.
// R5 proved the body correct; its 362 us was purely the (1024,8)->32-VGPR
// spill (480 MB scratch).
//
// 2 rows/block keeps W3 L2 traffic at 1 MiB/row (2 MiB/block over 2 rows)
// despite the second pass.  Pass-2 recompute is bit-identical math and
// slightly MORE accurate than baseline (normalizes unrounded fp32 y).
//
// Ownership (per row): thread t owns features f = c*4096 + t*4 + {0..3};
// p = c*512 + (t>>1), k = (t&1)*4 + d.  W3[(c*4+d)*1024+t] = folded bf16x8
// coeffs; GB3[c*1024+t] = packed gamma/beta.
// ---------------------------------------------------------------------------

#define LN_EPS 1e-5f

typedef float vfloat4 __attribute__((ext_vector_type(4)));

__device__ __forceinline__ unsigned bf16_rne(float f) {
    unsigned u = __float_as_uint(f);
    unsigned r = u + 0x7fffu + ((u >> 16) & 1u);
    return r >> 16;
}
__device__ __forceinline__ float bf_lo(unsigned u) { return __uint_as_float(u << 16); }
__device__ __forceinline__ float bf_hi(unsigned u) { return __uint_as_float(u & 0xffff0000u); }

// Prologue 1: fold poly into kernel, bf16-pack over m, permute so the main
// kernel's load for (c,d) at lane t is W3[(c*4+d)*1024 + t].
__global__ void fold_weights_kernel(const float* __restrict__ K,
                                    const float* __restrict__ poly,
                                    uint4* __restrict__ W3) {
    int tid = blockIdx.x * blockDim.x + threadIdx.x;   // [0, 65536)
    int p = tid >> 3, k = tid & 7;
    const float* kp = K + (size_t)p * 64 + k;          // stride 8 over m
    float pw = poly[p * 8 + k];
    float v[8];
#pragma unroll
    for (int m = 0; m < 8; ++m) v[m] = kp[m * 8] * pw;
    uint4 q;
    q.x = bf16_rne(v[0]) | (bf16_rne(v[1]) << 16);
    q.y = bf16_rne(v[2]) | (bf16_rne(v[3]) << 16);
    q.z = bf16_rne(v[4]) | (bf16_rne(v[5]) << 16);
    q.w = bf16_rne(v[6]) | (bf16_rne(v[7]) << 16);
    int c = p >> 9;
    int t = ((p & 511) << 1) | (k >> 2);
    int d = k & 3;
    W3[(c * 4 + d) * 1024 + t] = q;
}

// Prologue 2: GB3[tid] covers features f = tid*4 .. +3; each word packs
// (bf16(gamma) | bf16(beta)<<16).
__global__ void pack_gb_kernel(const float* __restrict__ gamma,
                               const float* __restrict__ beta,
                               uint4* __restrict__ GB3) {
    int tid = blockIdx.x * blockDim.x + threadIdx.x;   // [0, 16384)
    float4 g = ((const float4*)gamma)[tid];
    float4 b = ((const float4*)beta)[tid];
    uint4 q;
    q.x = bf16_rne(g.x) | (bf16_rne(b.x) << 16);
    q.y = bf16_rne(g.y) | (bf16_rne(b.y) << 16);
    q.z = bf16_rne(g.z) | (bf16_rne(b.z) << 16);
    q.w = bf16_rne(g.w) | (bf16_rne(b.w) << 16);
    GB3[tid] = q;
}

// Shared-unpack dot: 8 bf16 coeffs from q feed BOTH rows' accumulators.
// Requires Ta1..Ta7 / Tb1..Tb7 in scope.
#define CHEB_DOT2(q, accA, accB)                                              \
    {                                                                         \
        float c0 = bf_lo(q.x), c1 = bf_hi(q.x);                               \
        float c2 = bf_lo(q.y), c3 = bf_hi(q.y);                               \
        float c4 = bf_lo(q.z), c5 = bf_hi(q.z);                               \
        float c6 = bf_lo(q.w), c7 = bf_hi(q.w);                               \
        accA = fmaf(Ta1, c1, c0);   accB = fmaf(Tb1, c1, c0);                 \
        accA = fmaf(Ta2, c2, accA); accB = fmaf(Tb2, c2, accB);               \
        accA = fmaf(Ta3, c3, accA); accB = fmaf(Tb3, c3, accB);               \
        accA = fmaf(Ta4, c4, accA); accB = fmaf(Tb4, c4, accB);               \
        accA = fmaf(Ta5, c5, accA); accB = fmaf(Tb5, c5, accB);               \
        accA = fmaf(Ta6, c6, accA); accB = fmaf(Tb6, c6, accB);               \
        accA = fmaf(Ta7, c7, accA); accB = fmaf(Tb7, c7, accB);               \
    }

// Chebyshev T1..T7 for both rows from xs values va, vb.
#define CHEB_TERMS(va, vb)                                                    \
    float va2 = va + va, vb2 = vb + vb;                                       \
    float Ta1 = va, Tb1 = vb;                                                 \
    float Ta2 = fmaf(va2, Ta1, -1.f),  Tb2 = fmaf(vb2, Tb1, -1.f);            \
    float Ta3 = fmaf(va2, Ta2, -Ta1), Tb3 = fmaf(vb2, Tb2, -Tb1);             \
    float Ta4 = fmaf(va2, Ta3, -Ta2), Tb4 = fmaf(vb2, Tb3, -Tb2);             \
    float Ta5 = fmaf(va2, Ta4, -Ta3), Tb5 = fmaf(vb2, Tb4, -Tb3);             \
    float Ta6 = fmaf(va2, Ta5, -Ta4), Tb6 = fmaf(vb2, Tb5, -Tb4);             \
    float Ta7 = fmaf(va2, Ta6, -Ta5), Tb7 = fmaf(vb2, Tb6, -Tb5)

// Main: one block (1024 threads) per TWO rows; 512 blocks.  (1024,4) ->
// compiler's empirical 64-VGPR target; live set ~40 fits -> no spill,
// 2 blocks/CU.
__global__ __launch_bounds__(1024, 4) void cheb_ln_main(
    const float* __restrict__ x, const float* __restrict__ scale,
    const uint4* __restrict__ W3, const uint4* __restrict__ GB3,
    float* __restrict__ out) {
    __shared__ float xs[2][8192];
    __shared__ float red[64];
    const int r0 = blockIdx.x << 1;
    const int t = threadIdx.x;
    const int w = t >> 6, l = t & 63;
    const int phalf = t >> 1;

    // Stage xs[r][h*1024+i] = x[r][i] * scale[h][i]; scale loaded once for
    // both rows.  Coalesced; readback is 2-way same-address (free).
    float xv0 = x[(size_t)r0 * 1024 + t];
    float xv1 = x[(size_t)(r0 + 1) * 1024 + t];
#pragma unroll
    for (int h = 0; h < 8; ++h) {
        float s = scale[h * 1024 + t];
        xs[0][h * 1024 + t] = xv0 * s;
        xs[1][h * 1024 + t] = xv1 * s;
    }
    __syncthreads();

    // ---- Pass 1: sum / sumsq only (no y materialization) ----
    float sum0 = 0.f, sq0 = 0.f, sum1 = 0.f, sq1 = 0.f;
#pragma unroll
    for (int c = 0; c < 16; ++c) {
        float va = xs[0][c * 512 + phalf];
        float vb = xs[1][c * 512 + phalf];
        CHEB_TERMS(va, vb);
        // Quads 2-at-a-time: load latency overlaps the previous dot.
        {
            uint4 q0 = W3[(c * 4 + 0) * 1024 + t];
            uint4 q1 = W3[(c * 4 + 1) * 1024 + t];
            float a, b;
            CHEB_DOT2(q0, a, b);
            sum0 += a; sq0 = fmaf(a, a, sq0);
            sum1 += b; sq1 = fmaf(b, b, sq1);
            CHEB_DOT2(q1, a, b);
            sum0 += a; sq0 = fmaf(a, a, sq0);
            sum1 += b; sq1 = fmaf(b, b, sq1);
        }
        {
            uint4 q2 = W3[(c * 4 + 2) * 1024 + t];
            uint4 q3 = W3[(c * 4 + 3) * 1024 + t];
            float a, b;
            CHEB_DOT2(q2, a, b);
            sum0 += a; sq0 = fmaf(a, a, sq0);
            sum1 += b; sq1 = fmaf(b, b, sq1);
            CHEB_DOT2(q3, a, b);
            sum0 += a; sq0 = fmaf(a, a, sq0);
            sum1 += b; sq1 = fmaf(b, b, sq1);
        }
    }

    // Wave reduce (64 lanes), then cross-wave via LDS.
#pragma unroll
    for (int off = 32; off; off >>= 1) {
        sum0 += __shfl_down(sum0, off, 64);
        sq0  += __shfl_down(sq0,  off, 64);
        sum1 += __shfl_down(sum1, off, 64);
        sq1  += __shfl_down(sq1,  off, 64);
    }
    if (l == 0) {
        red[w * 4 + 0] = sum0; red[w * 4 + 1] = sq0;
        red[w * 4 + 2] = sum1; red[w * 4 + 3] = sq1;
    }
    __syncthreads();
    float S0 = 0.f, Q0 = 0.f, S1 = 0.f, Q1 = 0.f;
#pragma unroll
    for (int q = 0; q < 16; ++q) {
        S0 += red[q * 4 + 0]; Q0 += red[q * 4 + 1];
        S1 += red[q * 4 + 2]; Q1 += red[q * 4 + 3];
    }
    const float inv = 1.f / 65536.f;
    float mu0 = S0 * inv, mu1 = S1 * inv;
    float rs0 = rsqrtf(fmaf(-mu0, mu0, Q0 * inv) + LN_EPS);
    float rs1 = rsqrtf(fmaf(-mu1, mu1, Q1 * inv) + LN_EPS);

    // ---- Pass 2: recompute y (W3 L2-hot), normalize, store both rows ----
    float* o0 = out + (size_t)r0 * 65536;
    float* o1 = o0 + 65536;
#pragma unroll
    for (int c = 0; c < 16; ++c) {
        float va = xs[0][c * 512 + phalf];
        float vb = xs[1][c * 512 + phalf];
        CHEB_TERMS(va, vb);

        float a0, a1, a2, a3, b0, b1, b2, b3;
        {
            uint4 q = W3[(c * 4 + 0) * 1024 + t];
            CHEB_DOT2(q, a0, b0);
        }
        {
            uint4 q = W3[(c * 4 + 1) * 1024 + t];
            CHEB_DOT2(q, a1, b1);
        }
        {
            uint4 q = W3[(c * 4 + 2) * 1024 + t];
            CHEB_DOT2(q, a2, b2);
        }
        {
            uint4 q = W3[(c * 4 + 3) * 1024 + t];
            CHEB_DOT2(q, a3, b3);
        }

        uint4 g = GB3[c * 1024 + t];
        vfloat4 oA;
        oA.x = fmaf((a0 - mu0) * rs0, bf_lo(g.x), bf_hi(g.x));
        oA.y = fmaf((a1 - mu0) * rs0, bf_lo(g.y), bf_hi(g.y));
        oA.z = fmaf((a2 - mu0) * rs0, bf_lo(g.z), bf_hi(g.z));
        oA.w = fmaf((a3 - mu0) * rs0, bf_lo(g.w), bf_hi(g.w));
        __builtin_nontemporal_store(oA, (vfloat4*)(o0 + c * 4096 + t * 4));
        vfloat4 oB;
        oB.x = fmaf((b0 - mu1) * rs1, bf_lo(g.x), bf_hi(g.x));
        oB.y = fmaf((b1 - mu1) * rs1, bf_lo(g.y), bf_hi(g.y));
        oB.z = fmaf((b2 - mu1) * rs1, bf_lo(g.z), bf_hi(g.z));
        oB.w = fmaf((b3 - mu1) * rs1, bf_lo(g.w), bf_hi(g.w));
        __builtin_nontemporal_store(oB, (vfloat4*)(o1 + c * 4096 + t * 4));
    }
}

extern "C" void kernel_launch(void* const* d_in, const int* in_sizes, int n_in,
                              void* d_out, int out_size, void* d_ws, size_t ws_size,
                              hipStream_t stream) {
    const float* x     = (const float*)d_in[0];   // [1024,1024]
    const float* scale = (const float*)d_in[1];   // [8,1024]
    const float* poly  = (const float*)d_in[2];   // [8,1024,8]
    const float* kern  = (const float*)d_in[3];   // [8,1024,8,8]
    const float* gamma = (const float*)d_in[4];   // [65536]
    const float* beta  = (const float*)d_in[5];   // [65536]
    float* out = (float*)d_out;

    uint4* W3  = (uint4*)d_ws;                          // 1 MiB
    uint4* GB3 = (uint4*)((char*)d_ws + (1u << 20));    // 256 KiB

    fold_weights_kernel<<<256, 256, 0, stream>>>(kern, poly, W3);
    pack_gb_kernel<<<64, 256, 0, stream>>>(gamma, beta, GB3);
    cheb_ln_main<<<512, 1024, 0, stream>>>(x, scale, W3, GB3, out);
}

// Round 8
// 322.819 us; speedup vs baseline: 4.1907x; 1.0774x over previous
//
#include <hip/hip_runtime.h>
#include <stdint.h>

// ---------------------------------------------------------------------------
// MultiHeadAdaptiveChebyshevLayer, round 10: exact R0 baseline kernel with
// ONE change — nontemporal stores replaced by regular (L2 write-back)
// stores.
//
// Evidence: compiler model (R2/R5/R6 counters) shows (1024,4) -> 64-VGPR
// target, so the R0 baseline A was already a 64-VGPR / 2-blocks-per-CU
// kernel with only a mild y2 spill; its ~105 us main already includes
// cross-block overlap.  Every structural variant (tight caps, two-pass,
// persistent) lost to it.  A's one non-overlappable cost: NT stores bypass
// L2, so each block's terminal 256 KB burst must drain to HBM before the
// waves can retire (vmcnt drain before s_endpgm) — dead CU tail time,
// phase-aligned across resident blocks.  Regular stores land in L2 and
// write back in the background while the next block computes.
//
// Ownership: thread t owns features f = c*4096 + t*4 + {0..3}, c = 0..15;
// p = c*512 + (t>>1), k = (t&1)*4 + d.  W3[(c*4+d)*1024+t] = folded bf16x8
// coeffs; GB3[c*1024+t] = packed gamma/beta.
// ---------------------------------------------------------------------------

#define LN_EPS 1e-5f

typedef float vfloat4 __attribute__((ext_vector_type(4)));

__device__ __forceinline__ unsigned bf16_rne(float f) {
    unsigned u = __float_as_uint(f);
    unsigned r = u + 0x7fffu + ((u >> 16) & 1u);
    return r >> 16;
}
__device__ __forceinline__ float bf_lo(unsigned u) { return __uint_as_float(u << 16); }
__device__ __forceinline__ float bf_hi(unsigned u) { return __uint_as_float(u & 0xffff0000u); }

// Prologue 1: fold poly into kernel, bf16-pack over m, permute so that the
// main kernel's load for (c,d) at lane t is W3[(c*4+d)*1024 + t].
__global__ void fold_weights_kernel(const float* __restrict__ K,
                                    const float* __restrict__ poly,
                                    uint4* __restrict__ W3) {
    int tid = blockIdx.x * blockDim.x + threadIdx.x;   // [0, 65536)
    int p = tid >> 3, k = tid & 7;
    const float* kp = K + (size_t)p * 64 + k;          // stride 8 over m
    float pw = poly[p * 8 + k];
    float v[8];
#pragma unroll
    for (int m = 0; m < 8; ++m) v[m] = kp[m * 8] * pw;
    uint4 q;
    q.x = bf16_rne(v[0]) | (bf16_rne(v[1]) << 16);
    q.y = bf16_rne(v[2]) | (bf16_rne(v[3]) << 16);
    q.z = bf16_rne(v[4]) | (bf16_rne(v[5]) << 16);
    q.w = bf16_rne(v[6]) | (bf16_rne(v[7]) << 16);
    int c = p >> 9;
    int t = ((p & 511) << 1) | (k >> 2);
    int d = k & 3;
    W3[(c * 4 + d) * 1024 + t] = q;
}

// Prologue 2: GB3[tid] covers features f = tid*4 .. +3, each word packs
// (bf16(gamma) | bf16(beta)<<16).  Main kernel reads GB3[c*1024 + t].
__global__ void pack_gb_kernel(const float* __restrict__ gamma,
                               const float* __restrict__ beta,
                               uint4* __restrict__ GB3) {
    int tid = blockIdx.x * blockDim.x + threadIdx.x;   // [0, 16384)
    float4 g = ((const float4*)gamma)[tid];
    float4 b = ((const float4*)beta)[tid];
    uint4 q;
    q.x = bf16_rne(g.x) | (bf16_rne(b.x) << 16);
    q.y = bf16_rne(g.y) | (bf16_rne(b.y) << 16);
    q.z = bf16_rne(g.z) | (bf16_rne(b.z) << 16);
    q.w = bf16_rne(g.w) | (bf16_rne(b.w) << 16);
    GB3[tid] = q;
}

// Main: one block (1024 threads) per batch row.
__global__ __launch_bounds__(1024, 4) void cheb_ln_main(
    const float* __restrict__ x, const float* __restrict__ scale,
    const uint4* __restrict__ W3, const uint4* __restrict__ GB3,
    float* __restrict__ out) {
    __shared__ float xs[8192];
    __shared__ float red[32];
    const int r = blockIdx.x;
    const int t = threadIdx.x;
    const int w = t >> 6, l = t & 63;

    // Stage xs[h*1024 + i] = x[i] * scale[h*1024 + i] into LDS (coalesced;
    // x[t] loaded once and reused across the 8 heads).
    float xv = x[(size_t)r * 1024 + t];
#pragma unroll
    for (int h = 0; h < 8; ++h)
        xs[h * 1024 + t] = xv * scale[h * 1024 + t];
    __syncthreads();

    const int phalf = t >> 1;   // p = c*512 + phalf
    unsigned y2[32];            // 64 y values as packed bf16 pairs
    float sum = 0.f, sq = 0.f;

#pragma unroll
    for (int c = 0; c < 16; ++c) {
        float v = xs[c * 512 + phalf];          // 2-way broadcast, no conflicts
        float T0 = 1.f, T1 = v;
        float v2 = v + v;
        float T2 = v2 * T1 - T0;
        float T3 = v2 * T2 - T1;
        float T4 = v2 * T3 - T2;
        float T5 = v2 * T4 - T3;
        float T6 = v2 * T5 - T4;
        float T7 = v2 * T6 - T5;

        uint4 q0 = W3[(c * 4 + 0) * 1024 + t];  // all four: 16 B lane stride
        uint4 q1 = W3[(c * 4 + 1) * 1024 + t];
        uint4 q2 = W3[(c * 4 + 2) * 1024 + t];
        uint4 q3 = W3[(c * 4 + 3) * 1024 + t];

        float a0, a1, a2, a3;
        {
            a0 = T0 * bf_lo(q0.x); a0 = fmaf(T1, bf_hi(q0.x), a0);
            a0 = fmaf(T2, bf_lo(q0.y), a0); a0 = fmaf(T3, bf_hi(q0.y), a0);
            a0 = fmaf(T4, bf_lo(q0.z), a0); a0 = fmaf(T5, bf_hi(q0.z), a0);
            a0 = fmaf(T6, bf_lo(q0.w), a0); a0 = fmaf(T7, bf_hi(q0.w), a0);
            a1 = T0 * bf_lo(q1.x); a1 = fmaf(T1, bf_hi(q1.x), a1);
            a1 = fmaf(T2, bf_lo(q1.y), a1); a1 = fmaf(T3, bf_hi(q1.y), a1);
            a1 = fmaf(T4, bf_lo(q1.z), a1); a1 = fmaf(T5, bf_hi(q1.z), a1);
            a1 = fmaf(T6, bf_lo(q1.w), a1); a1 = fmaf(T7, bf_hi(q1.w), a1);
            a2 = T0 * bf_lo(q2.x); a2 = fmaf(T1, bf_hi(q2.x), a2);
            a2 = fmaf(T2, bf_lo(q2.y), a2); a2 = fmaf(T3, bf_hi(q2.y), a2);
            a2 = fmaf(T4, bf_lo(q2.z), a2); a2 = fmaf(T5, bf_hi(q2.z), a2);
            a2 = fmaf(T6, bf_lo(q2.w), a2); a2 = fmaf(T7, bf_hi(q2.w), a2);
            a3 = T0 * bf_lo(q3.x); a3 = fmaf(T1, bf_hi(q3.x), a3);
            a3 = fmaf(T2, bf_lo(q3.y), a3); a3 = fmaf(T3, bf_hi(q3.y), a3);
            a3 = fmaf(T4, bf_lo(q3.z), a3); a3 = fmaf(T5, bf_hi(q3.z), a3);
            a3 = fmaf(T6, bf_lo(q3.w), a3); a3 = fmaf(T7, bf_hi(q3.w), a3);
        }
        sum += a0 + a1 + a2 + a3;
        sq = fmaf(a0, a0, sq); sq = fmaf(a1, a1, sq);
        sq = fmaf(a2, a2, sq); sq = fmaf(a3, a3, sq);
        y2[c * 2 + 0] = bf16_rne(a0) | (bf16_rne(a1) << 16);
        y2[c * 2 + 1] = bf16_rne(a2) | (bf16_rne(a3) << 16);
    }

    // Wave reduce (64 lanes) then cross-wave via LDS.
#pragma unroll
    for (int off = 32; off; off >>= 1) {
        sum += __shfl_down(sum, off, 64);
        sq  += __shfl_down(sq,  off, 64);
    }
    if (l == 0) { red[w] = sum; red[w + 16] = sq; }
    __syncthreads();
    float S = 0.f, SQ = 0.f;
#pragma unroll
    for (int q = 0; q < 16; ++q) { S += red[q]; SQ += red[q + 16]; }
    const float inv = 1.f / 65536.f;
    float mu = S * inv;
    float var = fmaf(-mu, mu, SQ * inv);
    float rstd = rsqrtf(var + LN_EPS);

    // Epilogue: unpack y, normalize, affine.  REGULAR stores (not NT):
    // they land in L2 and write back to HBM in the background while the
    // next block computes, instead of stalling this block's retirement.
    float* orow = out + (size_t)r * 65536;
#pragma unroll
    for (int c = 0; c < 16; ++c) {
        uint4 g = GB3[c * 1024 + t];
        unsigned u0 = y2[c * 2 + 0], u1 = y2[c * 2 + 1];
        vfloat4 o;
        o.x = fmaf((bf_lo(u0) - mu) * rstd, bf_lo(g.x), bf_hi(g.x));
        o.y = fmaf((bf_hi(u0) - mu) * rstd, bf_lo(g.y), bf_hi(g.y));
        o.z = fmaf((bf_lo(u1) - mu) * rstd, bf_lo(g.z), bf_hi(g.z));
        o.w = fmaf((bf_hi(u1) - mu) * rstd, bf_lo(g.w), bf_hi(g.w));
        *(vfloat4*)(orow + c * 4096 + t * 4) = o;
    }
}

extern "C" void kernel_launch(void* const* d_in, const int* in_sizes, int n_in,
                              void* d_out, int out_size, void* d_ws, size_t ws_size,
                              hipStream_t stream) {
    const float* x     = (const float*)d_in[0];   // [1024,1024]
    const float* scale = (const float*)d_in[1];   // [8,1024]
    const float* poly  = (const float*)d_in[2];   // [8,1024,8]
    const float* kern  = (const float*)d_in[3];   // [8,1024,8,8]
    const float* gamma = (const float*)d_in[4];   // [65536]
    const float* beta  = (const float*)d_in[5];   // [65536]
    float* out = (float*)d_out;

    uint4* W3  = (uint4*)d_ws;                          // 1 MiB
    uint4* GB3 = (uint4*)((char*)d_ws + (1u << 20));    // 256 KiB

    fold_weights_kernel<<<256, 256, 0, stream>>>(kern, poly, W3);
    pack_gb_kernel<<<64, 256, 0, stream>>>(gamma, beta, GB3);
    cheb_ln_main<<<1024, 1024, 0, stream>>>(x, scale, W3, GB3, out);
}